// Round 1
// baseline (1211.032 us; speedup 1.0000x reference)
//
#include <hip/hip_runtime.h>
#include <hip/hip_bf16.h>
#include <cstdint>
#include <cstddef>

#define B_ 2
#define S_ 2048
#define D_ 2048
#define H_ 16
#define DK_ 128
#define M_ (B_*S_)   // 4096

typedef __attribute__((ext_vector_type(8))) __bf16 bf16x8;
typedef __attribute__((ext_vector_type(4))) float f32x4;

__device__ __forceinline__ unsigned short f2bf(float f) {
  union { float f; unsigned int u; } v; v.f = f;
  unsigned int r = (v.u + 0x7fffu + ((v.u >> 16) & 1u)) >> 16;
  return (unsigned short)r;
}
__device__ __forceinline__ float bf2f(unsigned short b) {
  union { unsigned int u; float f; } v; v.u = ((unsigned int)b) << 16;
  return v.f;
}

// ---------------- fp32 -> bf16 ----------------
__global__ void cvt_bf16(const float* __restrict__ src, unsigned short* __restrict__ dst, int n) {
  int i = (blockIdx.x * blockDim.x + threadIdx.x) * 4;
  if (i + 3 < n) {
    float4 v = *(const float4*)(src + i);
    dst[i+0] = f2bf(v.x); dst[i+1] = f2bf(v.y);
    dst[i+2] = f2bf(v.z); dst[i+3] = f2bf(v.w);
  }
}

// ---------------- GEMM: C(MxN) = A(MxK) * Bt(NxK)^T ----------------
#define BM 128
#define BN 128
#define BK 32
#define LDP 40   // padded LDS row stride (elements)

template<int WRITE_BF16>
__global__ __launch_bounds__(256) void gemm_bt(const unsigned short* __restrict__ A,
                                               const unsigned short* __restrict__ Bt,
                                               void* __restrict__ Cout,
                                               int M, int N, int K) {
  __shared__ unsigned short sA[BM * LDP];
  __shared__ unsigned short sB[BN * LDP];
  const int tid  = threadIdx.x;
  const int lane = tid & 63;
  const int wid  = tid >> 6;
  const int wm = wid >> 1, wn = wid & 1;       // 2x2 wave grid
  const int quad = lane >> 4, l16 = lane & 15;
  const int bm = blockIdx.y * BM, bn = blockIdx.x * BN;

  f32x4 acc[4][4];
  #pragma unroll
  for (int i = 0; i < 4; ++i)
    #pragma unroll
    for (int j = 0; j < 4; ++j)
      acc[i][j] = (f32x4){0.f, 0.f, 0.f, 0.f};

  for (int k0 = 0; k0 < K; k0 += BK) {
    uint4 ra[2], rb[2];
    #pragma unroll
    for (int c = 0; c < 2; ++c) {
      int idx = tid + c * 256;          // 512 chunks of 8 elements
      int row = idx >> 2;               // 4 chunks per row (BK=32)
      int col = (idx & 3) * 8;
      ra[c] = *(const uint4*)(A  + (size_t)(bm + row) * K + k0 + col);
      rb[c] = *(const uint4*)(Bt + (size_t)(bn + row) * K + k0 + col);
    }
    __syncthreads();
    #pragma unroll
    for (int c = 0; c < 2; ++c) {
      int idx = tid + c * 256;
      int row = idx >> 2;
      int col = (idx & 3) * 8;
      *(uint4*)(sA + row * LDP + col) = ra[c];
      *(uint4*)(sB + row * LDP + col) = rb[c];
    }
    __syncthreads();

    bf16x8 af[4], bfr[4];
    #pragma unroll
    for (int i = 0; i < 4; ++i)
      af[i] = *(const bf16x8*)(sA + (wm * 64 + i * 16 + l16) * LDP + quad * 8);
    #pragma unroll
    for (int j = 0; j < 4; ++j)
      bfr[j] = *(const bf16x8*)(sB + (wn * 64 + j * 16 + l16) * LDP + quad * 8);
    #pragma unroll
    for (int i = 0; i < 4; ++i)
      #pragma unroll
      for (int j = 0; j < 4; ++j)
        acc[i][j] = __builtin_amdgcn_mfma_f32_16x16x32_bf16(af[i], bfr[j], acc[i][j], 0, 0, 0);
  }

  #pragma unroll
  for (int i = 0; i < 4; ++i) {
    int row = bm + wm * 64 + i * 16 + quad * 4;
    #pragma unroll
    for (int j = 0; j < 4; ++j) {
      int col = bn + wn * 64 + j * 16 + l16;
      #pragma unroll
      for (int r = 0; r < 4; ++r) {
        if (WRITE_BF16)
          ((unsigned short*)Cout)[(size_t)(row + r) * N + col] = f2bf(acc[i][j][r]);
        else
          ((float*)Cout)[(size_t)(row + r) * N + col] = acc[i][j][r];
      }
    }
  }
}

// ---------------- RoPE (in-place on bf16 Q and K) ----------------
__global__ void rope_kernel(unsigned short* __restrict__ Q, unsigned short* __restrict__ K,
                            const int* __restrict__ pos) {
  int idx = blockIdx.x * blockDim.x + threadIdx.x;  // B*S*H*64 threads
  int i = idx & 63;
  int h = (idx >> 6) & (H_ - 1);
  int s = (idx >> 10) & (S_ - 1);
  int b = idx >> 21;
  float p = (float)pos[s];
  // theta^(-i/64) = exp(-i * ln(10000)/64)
  float inv = expf(-(float)i * (9.210340371976184f / 64.0f));
  float ang = p * inv;
  float sn, cs;
  sincosf(ang, &sn, &cs);
  size_t base = (((size_t)b * S_ + s) * D_) + (size_t)h * DK_ + 2 * i;
  float x1 = bf2f(Q[base]), x2 = bf2f(Q[base + 1]);
  Q[base]     = f2bf(x1 * cs - x2 * sn);
  Q[base + 1] = f2bf(x1 * sn + x2 * cs);
  x1 = bf2f(K[base]); x2 = bf2f(K[base + 1]);
  K[base]     = f2bf(x1 * cs - x2 * sn);
  K[base + 1] = f2bf(x1 * sn + x2 * cs);
}

// ---------------- Flash attention (causal), bf16 MFMA ----------------
// Block: 256 threads = 4 waves; block handles 64 Q rows of one (b,h); wave = 16 rows.
// Key tiles of 32, K staged row-major in LDS, V staged transposed.
__global__ __launch_bounds__(256) void flash_attn(const unsigned short* __restrict__ Q,
                                                  const unsigned short* __restrict__ K,
                                                  const unsigned short* __restrict__ V,
                                                  unsigned short* __restrict__ O) {
  __shared__ unsigned short sK[32 * 136];    // 32 keys x 128 feats, padded
  __shared__ unsigned short sVt[128 * 40];   // 128 feats x 32 keys, padded
  __shared__ unsigned short sP[4 * 16 * 40]; // per-wave 16x32 P tile, padded

  const int tid = threadIdx.x, lane = tid & 63, wid = tid >> 6;
  const int quad = lane >> 4, l16 = lane & 15;
  const int qi = blockIdx.x & 31;            // S/64 = 32 q-blocks
  const int bh = blockIdx.x >> 5;
  const int h = bh & (H_ - 1), b = bh >> 4;
  const int q0 = qi * 64;
  const size_t base = ((size_t)b * S_) * D_ + (size_t)h * DK_;
  const unsigned short* Qg = Q + base;
  const unsigned short* Kg = K + base;
  const unsigned short* Vg = V + base;
  unsigned short* Og = O + base;
  const int qw = q0 + wid * 16;

  bf16x8 qf[4];
  #pragma unroll
  for (int kk = 0; kk < 4; ++kk)
    qf[kk] = *(const bf16x8*)(Qg + (size_t)(qw + l16) * D_ + kk * 32 + quad * 8);

  f32x4 Oacc[8];
  #pragma unroll
  for (int d = 0; d < 8; ++d) Oacc[d] = (f32x4){0.f, 0.f, 0.f, 0.f};
  float m_[4], l_[4];
  #pragma unroll
  for (int r = 0; r < 4; ++r) { m_[r] = -1e30f; l_[r] = 0.f; }
  const float scale = 0.08838834764831845f;  // 1/sqrt(128)

  const int nkb = (q0 + 64) / 32;
  for (int kb = 0; kb < nkb; ++kb) {
    const int k0 = kb * 32;
    uint4 rk[2], rv[2];
    #pragma unroll
    for (int c = 0; c < 2; ++c) {
      int idx = tid + c * 256;
      int row = idx >> 4;               // 0..31 (key)
      int col = (idx & 15) * 8;         // 0..120 (feat)
      rk[c] = *(const uint4*)(Kg + (size_t)(k0 + row) * D_ + col);
      rv[c] = *(const uint4*)(Vg + (size_t)(k0 + row) * D_ + col);
    }
    __syncthreads();   // previous iteration's LDS reads complete
    #pragma unroll
    for (int c = 0; c < 2; ++c) {
      int idx = tid + c * 256;
      int row = idx >> 4;
      int col = (idx & 15) * 8;
      *(uint4*)(sK + row * 136 + col) = rk[c];
      union { uint4 v; unsigned short s[8]; } u; u.v = rv[c];
      #pragma unroll
      for (int j = 0; j < 8; ++j) sVt[(col + j) * 40 + row] = u.s[j];
    }
    __syncthreads();

    // scores: two 16x16 tiles over keys [k0, k0+32)
    f32x4 sc0 = (f32x4){0.f,0.f,0.f,0.f}, sc1 = (f32x4){0.f,0.f,0.f,0.f};
    #pragma unroll
    for (int kk = 0; kk < 4; ++kk) {
      bf16x8 kf0 = *(const bf16x8*)(sK + (l16) * 136 + kk * 32 + quad * 8);
      bf16x8 kf1 = *(const bf16x8*)(sK + (16 + l16) * 136 + kk * 32 + quad * 8);
      sc0 = __builtin_amdgcn_mfma_f32_16x16x32_bf16(qf[kk], kf0, sc0, 0, 0, 0);
      sc1 = __builtin_amdgcn_mfma_f32_16x16x32_bf16(qf[kk], kf1, sc1, 0, 0, 0);
    }

    float p0[4], p1[4], alpha[4];
    #pragma unroll
    for (int r = 0; r < 4; ++r) {
      int rowg = qw + quad * 4 + r;
      float v0 = sc0[r] * scale, v1 = sc1[r] * scale;
      if (k0 + l16 > rowg)      v0 = -1e30f;
      if (k0 + 16 + l16 > rowg) v1 = -1e30f;
      float t = fmaxf(v0, v1);
      t = fmaxf(t, __shfl_xor(t, 1));
      t = fmaxf(t, __shfl_xor(t, 2));
      t = fmaxf(t, __shfl_xor(t, 4));
      t = fmaxf(t, __shfl_xor(t, 8));
      float mn = fmaxf(m_[r], t);
      alpha[r] = __expf(m_[r] - mn);
      m_[r] = mn;
      p0[r] = __expf(v0 - mn);
      p1[r] = __expf(v1 - mn);
      float rs = p0[r] + p1[r];
      rs += __shfl_xor(rs, 1);
      rs += __shfl_xor(rs, 2);
      rs += __shfl_xor(rs, 4);
      rs += __shfl_xor(rs, 8);
      l_[r] = l_[r] * alpha[r] + rs;
    }
    #pragma unroll
    for (int d = 0; d < 8; ++d)
      #pragma unroll
      for (int r = 0; r < 4; ++r)
        Oacc[d][r] *= alpha[r];

    unsigned short* sPw = sP + wid * 16 * 40;
    #pragma unroll
    for (int r = 0; r < 4; ++r) {
      sPw[(quad * 4 + r) * 40 + l16]      = f2bf(p0[r]);
      sPw[(quad * 4 + r) * 40 + 16 + l16] = f2bf(p1[r]);
    }
    __syncthreads();   // drain P writes (wave-private region, barrier is safe/simple)

    bf16x8 pf = *(const bf16x8*)(sPw + l16 * 40 + quad * 8);
    #pragma unroll
    for (int d = 0; d < 8; ++d) {
      bf16x8 vf = *(const bf16x8*)(sVt + (d * 16 + l16) * 40 + quad * 8);
      Oacc[d] = __builtin_amdgcn_mfma_f32_16x16x32_bf16(pf, vf, Oacc[d], 0, 0, 0);
    }
  }

  #pragma unroll
  for (int d = 0; d < 8; ++d)
    #pragma unroll
    for (int r = 0; r < 4; ++r) {
      int rowg = qw + quad * 4 + r;
      Og[(size_t)rowg * D_ + d * 16 + l16] = f2bf(Oacc[d][r] / l_[r]);
    }
}

// ---------------- launch ----------------
extern "C" void kernel_launch(void* const* d_in, const int* in_sizes, int n_in,
                              void* d_out, int out_size, void* d_ws, size_t ws_size,
                              hipStream_t stream) {
  const float* x  = (const float*)d_in[0];
  const float* Wq = (const float*)d_in[1];
  const float* Wk = (const float*)d_in[2];
  const float* Wv = (const float*)d_in[3];
  const float* Wo = (const float*)d_in[4];
  const int*  pos = (const int*)d_in[5];
  float* out = (float*)d_out;

  char* ws = (char*)d_ws;
  size_t off = 0;
  auto alloc = [&](size_t bytes) { void* p = ws + off; off += (bytes + 255) & ~255ULL; return p; };
  const size_t nx = (size_t)M_ * D_;   // 8,388,608
  const size_t nw = (size_t)D_ * D_;   // 4,194,304
  unsigned short* xb  = (unsigned short*)alloc(nx * 2);
  unsigned short* wqb = (unsigned short*)alloc(nw * 2);
  unsigned short* wkb = (unsigned short*)alloc(nw * 2);
  unsigned short* wvb = (unsigned short*)alloc(nw * 2);
  unsigned short* wob = (unsigned short*)alloc(nw * 2);
  unsigned short* Qb  = (unsigned short*)alloc(nx * 2);
  unsigned short* Kb  = (unsigned short*)alloc(nx * 2);
  unsigned short* Vb  = (unsigned short*)alloc(nx * 2);
  unsigned short* AOb = xb;  // alias: x_bf16 dead once V projection is done

  hipLaunchKernelGGL(cvt_bf16, dim3(nx / 1024), dim3(256), 0, stream, x,  xb,  (int)nx);
  hipLaunchKernelGGL(cvt_bf16, dim3(nw / 1024), dim3(256), 0, stream, Wq, wqb, (int)nw);
  hipLaunchKernelGGL(cvt_bf16, dim3(nw / 1024), dim3(256), 0, stream, Wk, wkb, (int)nw);
  hipLaunchKernelGGL(cvt_bf16, dim3(nw / 1024), dim3(256), 0, stream, Wv, wvb, (int)nw);
  hipLaunchKernelGGL(cvt_bf16, dim3(nw / 1024), dim3(256), 0, stream, Wo, wob, (int)nw);

  dim3 ggrid(D_ / BN, M_ / BM);  // (16, 32)
  hipLaunchKernelGGL((gemm_bt<1>), ggrid, dim3(256), 0, stream, xb, wqb, (void*)Qb, M_, D_, D_);
  hipLaunchKernelGGL((gemm_bt<1>), ggrid, dim3(256), 0, stream, xb, wkb, (void*)Kb, M_, D_, D_);
  hipLaunchKernelGGL((gemm_bt<1>), ggrid, dim3(256), 0, stream, xb, wvb, (void*)Vb, M_, D_, D_);

  hipLaunchKernelGGL(rope_kernel, dim3((B_ * S_ * H_ * 64) / 256), dim3(256), 0, stream, Qb, Kb, pos);

  hipLaunchKernelGGL(flash_attn, dim3(B_ * H_ * (S_ / 64)), dim3(256), 0, stream, Qb, Kb, Vb, AOb);

  hipLaunchKernelGGL((gemm_bt<0>), ggrid, dim3(256), 0, stream, AOb, wob, (void*)out, M_, D_, D_);
}

// Round 2
// 746.740 us; speedup vs baseline: 1.6218x; 1.6218x over previous
//
#include <hip/hip_runtime.h>
#include <hip/hip_bf16.h>
#include <cstdint>
#include <cstddef>

#define B_ 2
#define S_ 2048
#define D_ 2048
#define H_ 16
#define DK_ 128
#define M_ (B_*S_)   // 4096

typedef __attribute__((ext_vector_type(8))) __bf16 bf16x8;
typedef __attribute__((ext_vector_type(4))) float f32x4;

__device__ __forceinline__ unsigned short f2bf(float f) {
  union { float f; unsigned int u; } v; v.f = f;
  unsigned int r = (v.u + 0x7fffu + ((v.u >> 16) & 1u)) >> 16;
  return (unsigned short)r;
}
__device__ __forceinline__ float bf2f(unsigned short b) {
  union { unsigned int u; float f; } v; v.u = ((unsigned int)b) << 16;
  return v.f;
}

// async global->LDS, 16B per lane; lptr must be wave-uniform base (+ lane*16 implicit)
__device__ __forceinline__ void gld16(const void* g, void* l) {
  __builtin_amdgcn_global_load_lds(
      (const __attribute__((address_space(1))) unsigned int*)g,
      (__attribute__((address_space(3))) unsigned int*)l, 16, 0, 0);
}

// ---------------- fp32 -> bf16 ----------------
__global__ void cvt_bf16(const float* __restrict__ src, unsigned short* __restrict__ dst, int n) {
  int i = (blockIdx.x * blockDim.x + threadIdx.x) * 4;
  if (i + 3 < n) {
    float4 v = *(const float4*)(src + i);
    dst[i+0] = f2bf(v.x); dst[i+1] = f2bf(v.y);
    dst[i+2] = f2bf(v.z); dst[i+3] = f2bf(v.w);
  }
}

// ---------------- GEMM: C(MxN) = A(MxK) * Bt(NxK)^T, m97-style ----------------
// 128x128 tile, BK=32, unpadded LDS (conflict-free for b128 frag reads),
// global_load_lds width-16 staging. grid.z selects (Bt, C) pair for fused QKV.
template<int WRITE_BF16>
__global__ __launch_bounds__(256) void gemm_bt(const unsigned short* __restrict__ A,
                                               const unsigned short* __restrict__ W0,
                                               const unsigned short* __restrict__ W1,
                                               const unsigned short* __restrict__ W2,
                                               void* __restrict__ C0, void* __restrict__ C1,
                                               void* __restrict__ C2,
                                               int M, int N, int K) {
  __shared__ unsigned short sA[128 * 32];
  __shared__ unsigned short sB[128 * 32];
  const int z = blockIdx.z;
  const unsigned short* Bt = (z == 0) ? W0 : (z == 1) ? W1 : W2;
  void* Cout = (z == 0) ? C0 : (z == 1) ? C1 : C2;

  const int tid  = threadIdx.x;
  const int lane = tid & 63;
  const int wid  = tid >> 6;
  const int wm = wid >> 1, wn = wid & 1;
  const int quad = lane >> 4, l16 = lane & 15;
  const int bm = blockIdx.y * 128, bn = blockIdx.x * 128;
  const int srow = lane >> 2;          // 0..15
  const int scol = (lane & 3) * 8;     // 0,8,16,24

  f32x4 acc[4][4];
  #pragma unroll
  for (int i = 0; i < 4; ++i)
    #pragma unroll
    for (int j = 0; j < 4; ++j)
      acc[i][j] = (f32x4){0.f, 0.f, 0.f, 0.f};

  for (int k0 = 0; k0 < K; k0 += 32) {
    __syncthreads();   // previous iteration's frag reads complete
    #pragma unroll
    for (int p = 0; p < 2; ++p) {
      int row = p * 64 + wid * 16;
      gld16(A  + (size_t)(bm + row + srow) * K + k0 + scol, sA + row * 32);
      gld16(Bt + (size_t)(bn + row + srow) * K + k0 + scol, sB + row * 32);
    }
    __syncthreads();   // drains vmcnt -> LDS populated

    bf16x8 af[4], bfr[4];
    #pragma unroll
    for (int i = 0; i < 4; ++i)
      af[i] = *(const bf16x8*)(sA + (wm * 64 + i * 16 + l16) * 32 + quad * 8);
    #pragma unroll
    for (int j = 0; j < 4; ++j)
      bfr[j] = *(const bf16x8*)(sB + (wn * 64 + j * 16 + l16) * 32 + quad * 8);
    #pragma unroll
    for (int i = 0; i < 4; ++i)
      #pragma unroll
      for (int j = 0; j < 4; ++j)
        acc[i][j] = __builtin_amdgcn_mfma_f32_16x16x32_bf16(af[i], bfr[j], acc[i][j], 0, 0, 0);
  }

  #pragma unroll
  for (int i = 0; i < 4; ++i) {
    int row = bm + wm * 64 + i * 16 + quad * 4;
    #pragma unroll
    for (int j = 0; j < 4; ++j) {
      int col = bn + wn * 64 + j * 16 + l16;
      #pragma unroll
      for (int r = 0; r < 4; ++r) {
        if (WRITE_BF16)
          ((unsigned short*)Cout)[(size_t)(row + r) * N + col] = f2bf(acc[i][j][r]);
        else
          ((float*)Cout)[(size_t)(row + r) * N + col] = acc[i][j][r];
      }
    }
  }
}

// ---------------- RoPE (in-place on bf16 Q and K) ----------------
__global__ void rope_kernel(unsigned short* __restrict__ Q, unsigned short* __restrict__ K,
                            const int* __restrict__ pos) {
  int idx = blockIdx.x * blockDim.x + threadIdx.x;
  int i = idx & 63;
  int h = (idx >> 6) & (H_ - 1);
  int s = (idx >> 10) & (S_ - 1);
  int b = idx >> 21;
  float p = (float)pos[s];
  float inv = expf(-(float)i * (9.210340371976184f / 64.0f));
  float ang = p * inv;
  float sn, cs;
  sincosf(ang, &sn, &cs);
  size_t base = (((size_t)b * S_ + s) * D_) + (size_t)h * DK_ + 2 * i;
  float x1 = bf2f(Q[base]), x2 = bf2f(Q[base + 1]);
  Q[base]     = f2bf(x1 * cs - x2 * sn);
  Q[base + 1] = f2bf(x1 * sn + x2 * cs);
  x1 = bf2f(K[base]); x2 = bf2f(K[base + 1]);
  K[base]     = f2bf(x1 * cs - x2 * sn);
  K[base + 1] = f2bf(x1 * sn + x2 * cs);
}

// ---------------- Flash attention (causal), 64-key tiles, swizzled V^T ----------------
// Block: 4 waves, 64 Q rows (16/wave). qi reversed so heavy blocks dispatch first.
__global__ __launch_bounds__(256) void flash_attn(const unsigned short* __restrict__ Q,
                                                  const unsigned short* __restrict__ K,
                                                  const unsigned short* __restrict__ V,
                                                  unsigned short* __restrict__ O) {
  __shared__ unsigned short sK[64 * 136];   // 64 keys x 128 feats, padded (17.4 KB)
  __shared__ unsigned short sVt[128 * 64];  // [feat][key^swz], XOR-swizzled (16 KB)
  __shared__ unsigned short sP[4 * 16 * 72];// per-wave 16x64 P, padded (9.2 KB)

  const int tid = threadIdx.x, lane = tid & 63, wid = tid >> 6;
  const int quad = lane >> 4, l16 = lane & 15, l8 = l16 >> 3;
  const int qi = 31 - (blockIdx.x & 31);    // reversed: heavy first
  const int bh = blockIdx.x >> 5;
  const int h = bh & (H_ - 1), b = bh >> 4;
  const int q0 = qi * 64;
  const size_t base = ((size_t)b * S_) * D_ + (size_t)h * DK_;
  const unsigned short* Qg = Q + base;
  const unsigned short* Kg = K + base;
  const unsigned short* Vg = V + base;
  unsigned short* Og = O + base;
  const int qw = q0 + wid * 16;

  bf16x8 qf[4];
  #pragma unroll
  for (int kk = 0; kk < 4; ++kk)
    qf[kk] = *(const bf16x8*)(Qg + (size_t)(qw + l16) * D_ + kk * 32 + quad * 8);

  f32x4 Oacc[8];
  #pragma unroll
  for (int d = 0; d < 8; ++d) Oacc[d] = (f32x4){0.f, 0.f, 0.f, 0.f};
  float m_[4], l_[4];
  #pragma unroll
  for (int r = 0; r < 4; ++r) { m_[r] = -1e30f; l_[r] = 0.f; }
  const float scale = 0.08838834764831845f;  // 1/sqrt(128)
  unsigned short* sPw = sP + wid * 16 * 72;

  for (int kb = 0; kb <= qi; ++kb) {
    const int k0 = kb * 64;
    uint4 rk[4], rv[4];
    #pragma unroll
    for (int c = 0; c < 4; ++c) {
      int idx = tid + c * 256;
      int row = idx >> 4;               // key 0..63
      int col = (idx & 15) * 8;         // feat 0..120
      rk[c] = *(const uint4*)(Kg + (size_t)(k0 + row) * D_ + col);
      rv[c] = *(const uint4*)(Vg + (size_t)(k0 + row) * D_ + col);
    }
    __syncthreads();   // previous iteration's sK/sVt reads complete
    #pragma unroll
    for (int c = 0; c < 4; ++c) {
      int idx = tid + c * 256;
      int row = idx >> 4;
      int colb = idx & 15;
      int col = colb * 8;
      *(uint4*)(sK + row * 136 + col) = rk[c];
      int swz = (colb & 7) * 8;
      union { uint4 v; unsigned short s[8]; } u; u.v = rv[c];
      #pragma unroll
      for (int j = 0; j < 8; ++j)
        sVt[(size_t)(col + j) * 64 + (row ^ swz)] = u.s[j];
    }
    __syncthreads();

    // scores: 4 x 16-key sub-tiles
    f32x4 sc[4];
    #pragma unroll
    for (int t = 0; t < 4; ++t) sc[t] = (f32x4){0.f,0.f,0.f,0.f};
    #pragma unroll
    for (int kk = 0; kk < 4; ++kk) {
      #pragma unroll
      for (int t = 0; t < 4; ++t) {
        bf16x8 kf = *(const bf16x8*)(sK + (t * 16 + l16) * 136 + kk * 32 + quad * 8);
        sc[t] = __builtin_amdgcn_mfma_f32_16x16x32_bf16(qf[kk], kf, sc[t], 0, 0, 0);
      }
    }

    const bool diag = (kb == qi);
    float alpha[4];
    #pragma unroll
    for (int r = 0; r < 4; ++r) {
      int rowg = qw + quad * 4 + r;
      float v[4];
      #pragma unroll
      for (int t = 0; t < 4; ++t) v[t] = sc[t][r] * scale;
      if (diag) {
        #pragma unroll
        for (int t = 0; t < 4; ++t)
          if (k0 + t * 16 + l16 > rowg) v[t] = -1e30f;
      }
      float t0 = fmaxf(fmaxf(v[0], v[1]), fmaxf(v[2], v[3]));
      t0 = fmaxf(t0, __shfl_xor(t0, 1));
      t0 = fmaxf(t0, __shfl_xor(t0, 2));
      t0 = fmaxf(t0, __shfl_xor(t0, 4));
      t0 = fmaxf(t0, __shfl_xor(t0, 8));
      float mn = fmaxf(m_[r], t0);
      alpha[r] = __expf(m_[r] - mn);
      m_[r] = mn;
      float rs = 0.f;
      #pragma unroll
      for (int t = 0; t < 4; ++t) {
        float e = __expf(v[t] - mn);
        rs += e;
        sPw[(quad * 4 + r) * 72 + t * 16 + l16] = f2bf(e);
      }
      rs += __shfl_xor(rs, 1);
      rs += __shfl_xor(rs, 2);
      rs += __shfl_xor(rs, 4);
      rs += __shfl_xor(rs, 8);
      l_[r] = l_[r] * alpha[r] + rs;
    }
    #pragma unroll
    for (int d = 0; d < 8; ++d)
      #pragma unroll
      for (int r = 0; r < 4; ++r)
        Oacc[d][r] *= alpha[r];

    // PV: P (A-frag, wave-private LDS; compiler inserts lgkmcnt wait) x V^T (B-frag)
    #pragma unroll
    for (int t2 = 0; t2 < 2; ++t2) {
      bf16x8 pf = *(const bf16x8*)(sPw + l16 * 72 + t2 * 32 + quad * 8);
      #pragma unroll
      for (int d = 0; d < 8; ++d) {
        int mr = (2 * d + l8) & 7;
        bf16x8 vf = *(const bf16x8*)(sVt + (size_t)(d * 16 + l16) * 64 + (((t2 * 4 + quad) ^ mr) << 3));
        Oacc[d] = __builtin_amdgcn_mfma_f32_16x16x32_bf16(pf, vf, Oacc[d], 0, 0, 0);
      }
    }
  }

  #pragma unroll
  for (int d = 0; d < 8; ++d)
    #pragma unroll
    for (int r = 0; r < 4; ++r) {
      int rowg = qw + quad * 4 + r;
      Og[(size_t)rowg * D_ + d * 16 + l16] = f2bf(Oacc[d][r] / l_[r]);
    }
}

// ---------------- launch ----------------
extern "C" void kernel_launch(void* const* d_in, const int* in_sizes, int n_in,
                              void* d_out, int out_size, void* d_ws, size_t ws_size,
                              hipStream_t stream) {
  const float* x  = (const float*)d_in[0];
  const float* Wq = (const float*)d_in[1];
  const float* Wk = (const float*)d_in[2];
  const float* Wv = (const float*)d_in[3];
  const float* Wo = (const float*)d_in[4];
  const int*  pos = (const int*)d_in[5];
  float* out = (float*)d_out;

  char* ws = (char*)d_ws;
  size_t off = 0;
  auto alloc = [&](size_t bytes) { void* p = ws + off; off += (bytes + 255) & ~255ULL; return p; };
  const size_t nx = (size_t)M_ * D_;
  const size_t nw = (size_t)D_ * D_;
  unsigned short* xb  = (unsigned short*)alloc(nx * 2);
  unsigned short* wqb = (unsigned short*)alloc(nw * 2);
  unsigned short* wkb = (unsigned short*)alloc(nw * 2);
  unsigned short* wvb = (unsigned short*)alloc(nw * 2);
  unsigned short* wob = (unsigned short*)alloc(nw * 2);
  unsigned short* Qb  = (unsigned short*)alloc(nx * 2);
  unsigned short* Kb  = (unsigned short*)alloc(nx * 2);
  unsigned short* Vb  = (unsigned short*)alloc(nx * 2);
  unsigned short* AOb = xb;  // alias: x_bf16 dead after QKV projection

  hipLaunchKernelGGL(cvt_bf16, dim3(nx / 1024), dim3(256), 0, stream, x,  xb,  (int)nx);
  hipLaunchKernelGGL(cvt_bf16, dim3(nw / 1024), dim3(256), 0, stream, Wq, wqb, (int)nw);
  hipLaunchKernelGGL(cvt_bf16, dim3(nw / 1024), dim3(256), 0, stream, Wk, wkb, (int)nw);
  hipLaunchKernelGGL(cvt_bf16, dim3(nw / 1024), dim3(256), 0, stream, Wv, wvb, (int)nw);
  hipLaunchKernelGGL(cvt_bf16, dim3(nw / 1024), dim3(256), 0, stream, Wo, wob, (int)nw);

  // fused QKV projection: grid.z = 3
  hipLaunchKernelGGL((gemm_bt<1>), dim3(D_ / 128, M_ / 128, 3), dim3(256), 0, stream,
                     xb, wqb, wkb, wvb, (void*)Qb, (void*)Kb, (void*)Vb, M_, D_, D_);

  hipLaunchKernelGGL(rope_kernel, dim3((B_ * S_ * H_ * 64) / 256), dim3(256), 0, stream, Qb, Kb, pos);

  hipLaunchKernelGGL(flash_attn, dim3(B_ * H_ * (S_ / 64)), dim3(256), 0, stream, Qb, Kb, Vb, AOb);

  hipLaunchKernelGGL((gemm_bt<0>), dim3(D_ / 128, M_ / 128, 1), dim3(256), 0, stream,
                     AOb, wob, wob, wob, (void*)out, (void*)out, (void*)out, M_, D_, D_);
}